// Round 1
// baseline (35.427 us; speedup 1.0000x reference)
//
#include <hip/hip_runtime.h>

// YOLO loss, MI355X. Dense part: softplus sums over obj+cls channels
// (21 of 25 planes per anchor -> skip box planes, 16% BW saved).
// Sparse part: <=1920 winner cells/scale from targets (last-valid-wins scan
// semantics), each needing 6 scattered pred loads.

#define NB 32      // batch
#define NT 60      // targets per image
#define NC 20      // classes
#define THREADS 256

// dense-sum blocks per scale (proportional to element counts 76.2/19/4.8%)
#define B0 1560
#define B1 390
#define B2 98
#define SUMB (B0 + B1 + B2)   // 2048
#define TGTB 96               // 3 scales * 32 batches

__constant__ float c_anch[3][3][2] = {
  {{10.f/640.f, 13.f/640.f}, {16.f/640.f, 30.f/640.f}, {33.f/640.f, 23.f/640.f}},
  {{30.f/640.f, 61.f/640.f}, {62.f/640.f, 45.f/640.f}, {59.f/640.f, 119.f/640.f}},
  {{116.f/640.f, 90.f/640.f}, {156.f/640.f, 198.f/640.f}, {373.f/640.f, 326.f/640.f}},
};

__device__ __forceinline__ float softplus0(float x) {
  // bce(x, 0) = max(x,0) + log1p(exp(-|x|))
  return fmaxf(x, 0.f) + __logf(1.f + __expf(-fabsf(x)));
}
__device__ __forceinline__ float sigm(float x) {
  return 1.f / (1.f + __expf(-x));
}

// ---- dense softplus sums over obj (cr==0) and cls (cr=1..20) planes ----
// useful planes per scale: NB * (3 anchors * 21 ch) = 2016; element i4 maps:
// plane = i4/HW, n = plane/63, a = (plane%63)/21, cr = (plane%63)%21,
// ch = a*25 + 4 + cr.
template<int HW>
__device__ void sum_scale(const float* __restrict__ p, int bl, int nb,
                          float* __restrict__ outp) {
  const int totalF4 = 504 * HW;  // 2016*HW/4
  float accO = 0.f, accC = 0.f;
  int tid = bl * THREADS + (int)threadIdx.x;
  int stride = nb * THREADS;
  for (int i = tid; i < totalF4; i += stride) {
    int i4 = i * 4;
    int plane = i4 / HW;           // compile-time-constant divisor
    int off = i4 - plane * HW;
    int n = plane / 63;
    int r = plane - n * 63;
    int a = r / 21;
    int cr = r - a * 21;
    int ch = a * 25 + 4 + cr;
    const float4 v = *reinterpret_cast<const float4*>(
        p + (size_t)(n * 75 + ch) * HW + off);
    float s = softplus0(v.x) + softplus0(v.y) + softplus0(v.z) + softplus0(v.w);
    if (cr == 0) accO += s; else accC += s;
  }
  // block reduce (wave64 shfl then 4-wave LDS combine)
  for (int o = 32; o > 0; o >>= 1) {
    accO += __shfl_down(accO, o, 64);
    accC += __shfl_down(accC, o, 64);
  }
  __shared__ float sO[4], sC[4];
  int wid = threadIdx.x >> 6, lane = threadIdx.x & 63;
  if (lane == 0) { sO[wid] = accO; sC[wid] = accC; }
  __syncthreads();
  if (threadIdx.x == 0) {
    outp[0] = sO[0] + sO[1] + sO[2] + sO[3];
    outp[1] = sC[0] + sC[1] + sC[2] + sC[3];
  }
}

// ---- sparse target part: one block per (scale, n) ----
__device__ void target_block(const float* __restrict__ pred,
                             const float* __restrict__ tg,
                             int scale, int n, float* __restrict__ outp) {
  const int strd = 8 << scale;       // 8,16,32
  const int W = 80 >> scale;         // 80,40,20
  const int HW = W * W;
  __shared__ int s_key[64];
  __shared__ int s_val[64];
  int t = threadIdx.x;
  float boxterm = 0.f, objc = 0.f, clsc = 0.f, npos = 0.f;
  float bw = 0.f, bh = 0.f, dx = 0.f, dy = 0.f, clsf = 0.f;
  int gx = 0, gy = 0, best = 0;
  bool valid = false;
  if (t < 64) {
    if (t < NT) {
      const float* g = tg + ((size_t)n * NT + t) * 6;
      float x1 = g[0], y1 = g[1], x2 = g[2], y2 = g[3];
      clsf = g[5];
      valid = (x2 > x1) && (y2 > y1);
      float cx = (x1 + x2) * 0.5f, cy = (y1 + y2) * 0.5f;
      bw = x2 - x1; bh = y2 - y1;
      float fs = (float)strd;
      float gxf = cx / fs, gyf = cy / fs;
      float wm1 = (float)(W - 1);
      gx = (int)fminf(fmaxf(gxf, 0.f), wm1);   // clip then trunc, like astype
      gy = (int)fminf(fmaxf(gyf, 0.f), wm1);
      dx = gxf - (float)gx;                     // uses UNclipped gxf (ref)
      dy = gyf - (float)gy;
      float bi = -1e30f;
      for (int a = 0; a < 3; a++) {
        float aw = c_anch[scale][a][0], ah = c_anch[scale][a][1];
        float rw = bw / aw, rh = bh / ah;
        float il = fminf(rw, 1.f / (rw + 1e-6f)) * fminf(rh, 1.f / (rh + 1e-6f));
        if (il > bi) { bi = il; best = a; }     // strict > : first max (argmax)
      }
      s_key[t] = (best * W + gy) * W + gx;
      s_val[t] = valid ? 1 : 0;
    } else {
      s_key[t] = -1; s_val[t] = 0;
    }
  }
  __syncthreads();
  if (t < NT && valid) {
    // last valid target with same (anchor,gy,gx) wins (scan overwrite)
    bool win = true;
    int key = s_key[t];
    for (int u = t + 1; u < NT; ++u)
      if (s_val[u] && s_key[u] == key) { win = false; break; }
    if (win) {
      float aw = c_anch[scale][best][0], ah = c_anch[scale][best][1];
      const float* base = pred + (size_t)(n * 75 + best * 25) * HW + gy * W + gx;
      float tx = base[0];
      float ty = base[HW];
      float tw = base[2 * HW];
      float th = base[3 * HW];
      float ob = base[4 * HW];
      int clsi = (int)clsf;                     // trunc toward zero = astype
      bool clsok = (clsi >= 0) && (clsi < NC);
      int clscl = clsi < 0 ? 0 : (clsi > NC - 1 ? NC - 1 : clsi);
      float cv = base[(5 + clscl) * HW];
      float fs = (float)strd;
      // pred box
      float px = (2.f * sigm(tx) - 0.5f + (float)gx) * fs;
      float py = (2.f * sigm(ty) - 0.5f + (float)gy) * fs;
      float sw = 2.f * sigm(tw); float pw = sw * sw * aw * fs;
      float sh = 2.f * sigm(th); float ph = sh * sh * ah * fs;
      // target box (t_wh deliberately has NO stride factor, per reference)
      float qx = ((dx + 0.5f) + (float)gx) * fs;
      float qy = ((dy + 0.5f) + (float)gy) * fs;
      float rw = bw / aw; float qw = rw * rw * aw;
      float rh = bh / ah; float qh = rh * rh * ah;
      // iou_cxcywh
      float b1x1 = px - pw * 0.5f, b1x2 = px + pw * 0.5f;
      float b1y1 = py - ph * 0.5f, b1y2 = py + ph * 0.5f;
      float b2x1 = qx - qw * 0.5f, b2x2 = qx + qw * 0.5f;
      float b2y1 = qy - qh * 0.5f, b2y2 = qy + qh * 0.5f;
      float iw = fmaxf(fminf(b1x2, b2x2) - fmaxf(b1x1, b2x1), 0.f);
      float ih = fmaxf(fminf(b1y2, b2y2) - fmaxf(b1y1, b2y1), 0.f);
      float inter = iw * ih;
      float uni = (b1x2 - b1x1) * (b1y2 - b1y1)
                + (b2x2 - b2x1) * (b2y2 - b2y1) - inter + 1e-7f;
      float iou = inter / uni;
      boxterm = 1.f - iou;
      objc = -ob;                    // bce(x,1)-bce(x,0) = -x
      clsc = clsok ? -cv : 0.f;
      npos = 1.f;
    }
  }
  if (t < 64) {
    for (int o = 32; o > 0; o >>= 1) {
      boxterm += __shfl_down(boxterm, o, 64);
      objc    += __shfl_down(objc, o, 64);
      clsc    += __shfl_down(clsc, o, 64);
      npos    += __shfl_down(npos, o, 64);
    }
    if (t == 0) {
      outp[0] = boxterm; outp[1] = objc; outp[2] = clsc; outp[3] = npos;
    }
  }
}

__global__ __launch_bounds__(THREADS)
void yolo_main(const float* __restrict__ p0, const float* __restrict__ p1,
               const float* __restrict__ p2, const float* __restrict__ tg,
               float* __restrict__ ws) {
  int b = blockIdx.x;
  if (b < B0)             sum_scale<6400>(p0, b, B0, ws + 2 * (size_t)b);
  else if (b < B0 + B1)   sum_scale<1600>(p1, b - B0, B1, ws + 2 * (size_t)b);
  else if (b < SUMB)      sum_scale<400>(p2, b - (B0 + B1), B2, ws + 2 * (size_t)b);
  else {
    int g = b - SUMB;
    int scale = g / NB, n = g - scale * NB;
    const float* p = scale == 0 ? p0 : (scale == 1 ? p1 : p2);
    target_block(p, tg, scale, n, ws + 2 * SUMB + 4 * (size_t)g);
  }
}

__global__ __launch_bounds__(THREADS)
void yolo_final(const float* __restrict__ ws, float* __restrict__ out) {
  // reduce dense partials, split by per-scale block ranges
  float acc[6] = {0.f, 0.f, 0.f, 0.f, 0.f, 0.f};
  for (int b = threadIdx.x; b < SUMB; b += THREADS) {
    int s = (b < B0) ? 0 : (b < B0 + B1 ? 1 : 2);
    acc[2 * s]     += ws[2 * b];
    acc[2 * s + 1] += ws[2 * b + 1];
  }
  __shared__ float red[THREADS][6];
  for (int k = 0; k < 6; k++) red[threadIdx.x][k] = acc[k];
  __syncthreads();
  for (int off = THREADS / 2; off > 0; off >>= 1) {
    if ((int)threadIdx.x < off)
      for (int k = 0; k < 6; k++)
        red[threadIdx.x][k] += red[threadIdx.x + off][k];
    __syncthreads();
  }
  if (threadIdx.x == 0) {
    float tp[3][4];
    for (int s = 0; s < 3; s++)
      for (int k = 0; k < 4; k++) tp[s][k] = 0.f;
    const float* wt = ws + 2 * SUMB;
    for (int g = 0; g < TGTB; ++g) {
      int s = g / NB;
      for (int k = 0; k < 4; k++) tp[s][k] += wt[g * 4 + k];
    }
    const float objDen[3] = {614400.f, 153600.f, 38400.f};  // N*A*H*W
    float total = 0.f, lb = 0.f, lo = 0.f, lc = 0.f;
    for (int s = 0; s < 3; s++) {
      float np = tp[s][3];
      float lbs = tp[s][0] / fmaxf(np, 1.f);
      float los = (red[0][2 * s] + tp[s][1]) / objDen[s];
      float lcs = (np > 0.f)
                    ? (red[0][2 * s + 1] + tp[s][2]) / (objDen[s] * (float)NC)
                    : 0.f;
      total += 0.05f * lbs + 1.0f * los + 0.5f * lcs;
      lb += lbs; lo += los; lc += lcs;
    }
    out[0] = total; out[1] = lb; out[2] = lo; out[3] = lc;
  }
}

extern "C" void kernel_launch(void* const* d_in, const int* in_sizes, int n_in,
                              void* d_out, int out_size, void* d_ws, size_t ws_size,
                              hipStream_t stream) {
  const float* p0 = (const float*)d_in[0];
  const float* p1 = (const float*)d_in[1];
  const float* p2 = (const float*)d_in[2];
  const float* tg = (const float*)d_in[3];
  float* ws = (float*)d_ws;
  // every ws slot used is written each launch -> no memset needed; fully
  // deterministic (no float atomics, fixed reduction orders).
  yolo_main<<<SUMB + TGTB, THREADS, 0, stream>>>(p0, p1, p2, tg, ws);
  yolo_final<<<1, THREADS, 0, stream>>>(ws, (float*)d_out);
}

// Round 2
// 31.783 us; speedup vs baseline: 1.1146x; 1.1146x over previous
//
#include <hip/hip_runtime.h>

// YOLO loss, MI355X. Dense part: softplus sums over obj+cls channels
// (21 of 25 planes per anchor -> skip box planes, 16% BW saved).
// Sparse part: <=1920 winner cells/scale from targets (last-valid-wins scan
// semantics), each needing 6 scattered pred loads.
// R2: yolo_final fully parallelized (R1: thread-0 serial loads = 40us tail).

#define NB 32      // batch
#define NT 60      // targets per image
#define NC 20      // classes
#define THREADS 256

// dense-sum blocks per scale (proportional to element counts 76.2/19/4.8%)
#define B0 1560
#define B1 390
#define B2 98
#define SUMB (B0 + B1 + B2)   // 2048
#define TGTB 96               // 3 scales * 32 batches

__constant__ float c_anch[3][3][2] = {
  {{10.f/640.f, 13.f/640.f}, {16.f/640.f, 30.f/640.f}, {33.f/640.f, 23.f/640.f}},
  {{30.f/640.f, 61.f/640.f}, {62.f/640.f, 45.f/640.f}, {59.f/640.f, 119.f/640.f}},
  {{116.f/640.f, 90.f/640.f}, {156.f/640.f, 198.f/640.f}, {373.f/640.f, 326.f/640.f}},
};

__device__ __forceinline__ float softplus0(float x) {
  // bce(x, 0) = max(x,0) + log1p(exp(-|x|))
  return fmaxf(x, 0.f) + __logf(1.f + __expf(-fabsf(x)));
}
__device__ __forceinline__ float sigm(float x) {
  return 1.f / (1.f + __expf(-x));
}

// ---- dense softplus sums over obj (cr==0) and cls (cr=1..20) planes ----
// useful planes per scale: NB * (3 anchors * 21 ch) = 2016; element i4 maps:
// plane = i4/HW, n = plane/63, a = (plane%63)/21, cr = (plane%63)%21,
// ch = a*25 + 4 + cr.
template<int HW>
__device__ void sum_scale(const float* __restrict__ p, int bl, int nb,
                          float* __restrict__ outp) {
  const int totalF4 = 504 * HW;  // 2016*HW/4
  float accO = 0.f, accC = 0.f;
  int tid = bl * THREADS + (int)threadIdx.x;
  int stride = nb * THREADS;
  for (int i = tid; i < totalF4; i += stride) {
    int i4 = i * 4;
    int plane = i4 / HW;           // compile-time-constant divisor
    int off = i4 - plane * HW;
    int n = plane / 63;
    int r = plane - n * 63;
    int a = r / 21;
    int cr = r - a * 21;
    int ch = a * 25 + 4 + cr;
    const float4 v = *reinterpret_cast<const float4*>(
        p + (size_t)(n * 75 + ch) * HW + off);
    float s = softplus0(v.x) + softplus0(v.y) + softplus0(v.z) + softplus0(v.w);
    if (cr == 0) accO += s; else accC += s;
  }
  // block reduce (wave64 shfl then 4-wave LDS combine)
  for (int o = 32; o > 0; o >>= 1) {
    accO += __shfl_down(accO, o, 64);
    accC += __shfl_down(accC, o, 64);
  }
  __shared__ float sO[4], sC[4];
  int wid = threadIdx.x >> 6, lane = threadIdx.x & 63;
  if (lane == 0) { sO[wid] = accO; sC[wid] = accC; }
  __syncthreads();
  if (threadIdx.x == 0) {
    outp[0] = sO[0] + sO[1] + sO[2] + sO[3];
    outp[1] = sC[0] + sC[1] + sC[2] + sC[3];
  }
}

// ---- sparse target part: one block per (scale, n) ----
__device__ void target_block(const float* __restrict__ pred,
                             const float* __restrict__ tg,
                             int scale, int n, float* __restrict__ outp) {
  const int strd = 8 << scale;       // 8,16,32
  const int W = 80 >> scale;         // 80,40,20
  const int HW = W * W;
  __shared__ int s_key[64];
  __shared__ int s_val[64];
  int t = threadIdx.x;
  float boxterm = 0.f, objc = 0.f, clsc = 0.f, npos = 0.f;
  float bw = 0.f, bh = 0.f, dx = 0.f, dy = 0.f, clsf = 0.f;
  int gx = 0, gy = 0, best = 0;
  bool valid = false;
  if (t < 64) {
    if (t < NT) {
      const float* g = tg + ((size_t)n * NT + t) * 6;
      float x1 = g[0], y1 = g[1], x2 = g[2], y2 = g[3];
      clsf = g[5];
      valid = (x2 > x1) && (y2 > y1);
      float cx = (x1 + x2) * 0.5f, cy = (y1 + y2) * 0.5f;
      bw = x2 - x1; bh = y2 - y1;
      float fs = (float)strd;
      float gxf = cx / fs, gyf = cy / fs;
      float wm1 = (float)(W - 1);
      gx = (int)fminf(fmaxf(gxf, 0.f), wm1);   // clip then trunc, like astype
      gy = (int)fminf(fmaxf(gyf, 0.f), wm1);
      dx = gxf - (float)gx;                     // uses UNclipped gxf (ref)
      dy = gyf - (float)gy;
      float bi = -1e30f;
      for (int a = 0; a < 3; a++) {
        float aw = c_anch[scale][a][0], ah = c_anch[scale][a][1];
        float rw = bw / aw, rh = bh / ah;
        float il = fminf(rw, 1.f / (rw + 1e-6f)) * fminf(rh, 1.f / (rh + 1e-6f));
        if (il > bi) { bi = il; best = a; }     // strict > : first max (argmax)
      }
      s_key[t] = (best * W + gy) * W + gx;
      s_val[t] = valid ? 1 : 0;
    } else {
      s_key[t] = -1; s_val[t] = 0;
    }
  }
  __syncthreads();
  if (t < NT && valid) {
    // last valid target with same (anchor,gy,gx) wins (scan overwrite)
    bool win = true;
    int key = s_key[t];
    for (int u = t + 1; u < NT; ++u)
      if (s_val[u] && s_key[u] == key) { win = false; break; }
    if (win) {
      float aw = c_anch[scale][best][0], ah = c_anch[scale][best][1];
      const float* base = pred + (size_t)(n * 75 + best * 25) * HW + gy * W + gx;
      float tx = base[0];
      float ty = base[HW];
      float tw = base[2 * HW];
      float th = base[3 * HW];
      float ob = base[4 * HW];
      int clsi = (int)clsf;                     // trunc toward zero = astype
      bool clsok = (clsi >= 0) && (clsi < NC);
      int clscl = clsi < 0 ? 0 : (clsi > NC - 1 ? NC - 1 : clsi);
      float cv = base[(5 + clscl) * HW];
      float fs = (float)strd;
      // pred box
      float px = (2.f * sigm(tx) - 0.5f + (float)gx) * fs;
      float py = (2.f * sigm(ty) - 0.5f + (float)gy) * fs;
      float sw = 2.f * sigm(tw); float pw = sw * sw * aw * fs;
      float sh = 2.f * sigm(th); float ph = sh * sh * ah * fs;
      // target box (t_wh deliberately has NO stride factor, per reference)
      float qx = ((dx + 0.5f) + (float)gx) * fs;
      float qy = ((dy + 0.5f) + (float)gy) * fs;
      float rw = bw / aw; float qw = rw * rw * aw;
      float rh = bh / ah; float qh = rh * rh * ah;
      // iou_cxcywh
      float b1x1 = px - pw * 0.5f, b1x2 = px + pw * 0.5f;
      float b1y1 = py - ph * 0.5f, b1y2 = py + ph * 0.5f;
      float b2x1 = qx - qw * 0.5f, b2x2 = qx + qw * 0.5f;
      float b2y1 = qy - qh * 0.5f, b2y2 = qy + qh * 0.5f;
      float iw = fmaxf(fminf(b1x2, b2x2) - fmaxf(b1x1, b2x1), 0.f);
      float ih = fmaxf(fminf(b1y2, b2y2) - fmaxf(b1y1, b2y1), 0.f);
      float inter = iw * ih;
      float uni = (b1x2 - b1x1) * (b1y2 - b1y1)
                + (b2x2 - b2x1) * (b2y2 - b2y1) - inter + 1e-7f;
      float iou = inter / uni;
      boxterm = 1.f - iou;
      objc = -ob;                    // bce(x,1)-bce(x,0) = -x
      clsc = clsok ? -cv : 0.f;
      npos = 1.f;
    }
  }
  if (t < 64) {
    for (int o = 32; o > 0; o >>= 1) {
      boxterm += __shfl_down(boxterm, o, 64);
      objc    += __shfl_down(objc, o, 64);
      clsc    += __shfl_down(clsc, o, 64);
      npos    += __shfl_down(npos, o, 64);
    }
    if (t == 0) {
      outp[0] = boxterm; outp[1] = objc; outp[2] = clsc; outp[3] = npos;
    }
  }
}

__global__ __launch_bounds__(THREADS)
void yolo_main(const float* __restrict__ p0, const float* __restrict__ p1,
               const float* __restrict__ p2, const float* __restrict__ tg,
               float* __restrict__ ws) {
  int b = blockIdx.x;
  if (b < B0)             sum_scale<6400>(p0, b, B0, ws + 2 * (size_t)b);
  else if (b < B0 + B1)   sum_scale<1600>(p1, b - B0, B1, ws + 2 * (size_t)b);
  else if (b < SUMB)      sum_scale<400>(p2, b - (B0 + B1), B2, ws + 2 * (size_t)b);
  else {
    int g = b - SUMB;
    int scale = g / NB, n = g - scale * NB;
    const float* p = scale == 0 ? p0 : (scale == 1 ? p1 : p2);
    target_block(p, tg, scale, n, ws + 2 * SUMB + 4 * (size_t)g);
  }
}

// ---- parallel finalize ----
// acc layout: [0..5]   dense  {objSum,clsSum} per scale
//             [6..17]  target {box,objCorr,clsCorr,npos} per scale
__global__ __launch_bounds__(THREADS)
void yolo_final(const float* __restrict__ ws, float* __restrict__ out) {
  float acc[18];
#pragma unroll
  for (int k = 0; k < 18; k++) acc[k] = 0.f;
  int t = threadIdx.x;
  // dense partials: coalesced float2 strided loads
  for (int b = t; b < SUMB; b += THREADS) {
    int s = (b < B0) ? 0 : (b < B0 + B1 ? 1 : 2);
    const float2 v = *reinterpret_cast<const float2*>(ws + 2 * (size_t)b);
    acc[2 * s] += v.x;
    acc[2 * s + 1] += v.y;
  }
  // target partials: one float4 per thread (t < 96)
  if (t < TGTB) {
    int s = t / NB;
    const float4 v = *reinterpret_cast<const float4*>(ws + 2 * SUMB + 4 * (size_t)t);
    acc[6 + 4 * s + 0] += v.x;
    acc[6 + 4 * s + 1] += v.y;
    acc[6 + 4 * s + 2] += v.z;
    acc[6 + 4 * s + 3] += v.w;
  }
  // wave shfl reduce, then 4-wave LDS combine
#pragma unroll
  for (int o = 32; o > 0; o >>= 1)
#pragma unroll
    for (int k = 0; k < 18; k++) acc[k] += __shfl_down(acc[k], o, 64);
  __shared__ float red[4][18];
  int wid = t >> 6, lane = t & 63;
  if (lane == 0)
#pragma unroll
    for (int k = 0; k < 18; k++) red[wid][k] = acc[k];
  __syncthreads();
  if (t == 0) {
    float r[18];
#pragma unroll
    for (int k = 0; k < 18; k++)
      r[k] = red[0][k] + red[1][k] + red[2][k] + red[3][k];
    const float objDen[3] = {614400.f, 153600.f, 38400.f};  // N*A*H*W
    float total = 0.f, lb = 0.f, lo = 0.f, lc = 0.f;
    for (int s = 0; s < 3; s++) {
      float np = r[6 + 4 * s + 3];
      float lbs = r[6 + 4 * s + 0] / fmaxf(np, 1.f);
      float los = (r[2 * s] + r[6 + 4 * s + 1]) / objDen[s];
      float lcs = (np > 0.f)
                    ? (r[2 * s + 1] + r[6 + 4 * s + 2]) / (objDen[s] * (float)NC)
                    : 0.f;
      total += 0.05f * lbs + 1.0f * los + 0.5f * lcs;
      lb += lbs; lo += los; lc += lcs;
    }
    out[0] = total; out[1] = lb; out[2] = lo; out[3] = lc;
  }
}

extern "C" void kernel_launch(void* const* d_in, const int* in_sizes, int n_in,
                              void* d_out, int out_size, void* d_ws, size_t ws_size,
                              hipStream_t stream) {
  const float* p0 = (const float*)d_in[0];
  const float* p1 = (const float*)d_in[1];
  const float* p2 = (const float*)d_in[2];
  const float* tg = (const float*)d_in[3];
  float* ws = (float*)d_ws;
  // every ws slot used is written each launch -> no memset needed; fully
  // deterministic (no float atomics, fixed reduction orders).
  yolo_main<<<SUMB + TGTB, THREADS, 0, stream>>>(p0, p1, p2, tg, ws);
  yolo_final<<<1, THREADS, 0, stream>>>(ws, (float*)d_out);
}

// Round 3
// 25.002 us; speedup vs baseline: 1.4170x; 1.2712x over previous
//
#include <hip/hip_runtime.h>

// YOLO loss, MI355X.
// R3: dense pass restructured for ILP — per (n,anchor) group the 21 useful
// planes (obj+cls) are CONTIGUOUS in memory; every dense block processes
// exactly 2100 float4 with a compile-time-unrolled 8-deep load pipeline
// (R2 was latency-bound: runtime trip count -> 1 load in flight).
// Target blocks launched FIRST so their scattered-load latency overlaps.

#define NB 32      // batch
#define NT 60      // targets per image
#define NC 20      // classes
#define THREADS 256

#define TGTB 96               // 3 scales * 32 batches, blocks 0..95
// dense: 96 groups/scale * blocks-per-group {16,4,1}
#define D0 1536
#define D1 384
#define D2 96
#define DENSB (D0 + D1 + D2)  // 2016
#define PB 2100               // float4 per dense block (8*256 + 52)

// ws layout (floats): [0..383] target partials 96*4, [384..] dense 2016*2
#define WS_DENSE 384

__constant__ float c_anch[3][3][2] = {
  {{10.f/640.f, 13.f/640.f}, {16.f/640.f, 30.f/640.f}, {33.f/640.f, 23.f/640.f}},
  {{30.f/640.f, 61.f/640.f}, {62.f/640.f, 45.f/640.f}, {59.f/640.f, 119.f/640.f}},
  {{116.f/640.f, 90.f/640.f}, {156.f/640.f, 198.f/640.f}, {373.f/640.f, 326.f/640.f}},
};

__device__ __forceinline__ float softplus0(float x) {
  // bce(x, 0) = max(x,0) + log1p(exp(-|x|))
  return fmaxf(x, 0.f) + __logf(1.f + __expf(-fabsf(x)));
}
__device__ __forceinline__ float sp4(float4 v) {
  return softplus0(v.x) + softplus0(v.y) + softplus0(v.z) + softplus0(v.w);
}
__device__ __forceinline__ float sigm(float x) {
  return 1.f / (1.f + __expf(-x));
}

// ---- dense: block b covers f4 range [sub*PB, (sub+1)*PB) of group g's
// contiguous 21-plane chunk. obj = first plane (k < HW/4), else cls.
template<int HW, int LOG_BPG>
__device__ void sum_groups(const float* __restrict__ p, int b,
                           float* __restrict__ outp) {
  const int HW4 = HW / 4;
  int g = b >> LOG_BPG;
  int sub = b - (g << LOG_BPG);
  int n = g / 3;                 // magic-mul
  int a = g - n * 3;
  const float* bp = p + (size_t)(n * 75 + a * 25 + 4) * HW;
  int tid = threadIdx.x;
  int k0 = sub * PB + tid;
  float4 v[8];
#pragma unroll
  for (int u = 0; u < 8; ++u)
    v[u] = *reinterpret_cast<const float4*>(bp + 4 * (k0 + u * 256));
  float accO = 0.f, accC = 0.f;
#pragma unroll
  for (int u = 0; u < 8; ++u) {
    float s = sp4(v[u]);
    bool isO = (k0 + u * 256) < HW4;
    accO += isO ? s : 0.f;
    accC += isO ? 0.f : s;
  }
  if (tid < PB - 2048) {                       // 52-thread tail
    int k = sub * PB + 2048 + tid;
    float s = sp4(*reinterpret_cast<const float4*>(bp + 4 * k));
    bool isO = k < HW4;
    accO += isO ? s : 0.f;
    accC += isO ? 0.f : s;
  }
  // block reduce (wave64 shfl then 4-wave LDS combine)
#pragma unroll
  for (int o = 32; o > 0; o >>= 1) {
    accO += __shfl_down(accO, o, 64);
    accC += __shfl_down(accC, o, 64);
  }
  __shared__ float sO[4], sC[4];
  int wid = threadIdx.x >> 6, lane = threadIdx.x & 63;
  if (lane == 0) { sO[wid] = accO; sC[wid] = accC; }
  __syncthreads();
  if (threadIdx.x == 0) {
    outp[0] = sO[0] + sO[1] + sO[2] + sO[3];
    outp[1] = sC[0] + sC[1] + sC[2] + sC[3];
  }
}

// ---- sparse target part: one block per (scale, n) ----
__device__ void target_block(const float* __restrict__ pred,
                             const float* __restrict__ tg,
                             int scale, int n, float* __restrict__ outp) {
  const int strd = 8 << scale;       // 8,16,32
  const int W = 80 >> scale;         // 80,40,20
  const int HW = W * W;
  __shared__ int s_key[64];
  __shared__ int s_val[64];
  int t = threadIdx.x;
  float boxterm = 0.f, objc = 0.f, clsc = 0.f, npos = 0.f;
  float bw = 0.f, bh = 0.f, dx = 0.f, dy = 0.f, clsf = 0.f;
  int gx = 0, gy = 0, best = 0;
  bool valid = false;
  if (t < 64) {
    if (t < NT) {
      const float* g = tg + ((size_t)n * NT + t) * 6;
      float x1 = g[0], y1 = g[1], x2 = g[2], y2 = g[3];
      clsf = g[5];
      valid = (x2 > x1) && (y2 > y1);
      float cx = (x1 + x2) * 0.5f, cy = (y1 + y2) * 0.5f;
      bw = x2 - x1; bh = y2 - y1;
      float fs = (float)strd;
      float gxf = cx / fs, gyf = cy / fs;
      float wm1 = (float)(W - 1);
      gx = (int)fminf(fmaxf(gxf, 0.f), wm1);   // clip then trunc, like astype
      gy = (int)fminf(fmaxf(gyf, 0.f), wm1);
      dx = gxf - (float)gx;                     // uses UNclipped gxf (ref)
      dy = gyf - (float)gy;
      float bi = -1e30f;
      for (int a = 0; a < 3; a++) {
        float aw = c_anch[scale][a][0], ah = c_anch[scale][a][1];
        float rw = bw / aw, rh = bh / ah;
        float il = fminf(rw, 1.f / (rw + 1e-6f)) * fminf(rh, 1.f / (rh + 1e-6f));
        if (il > bi) { bi = il; best = a; }     // strict > : first max (argmax)
      }
      s_key[t] = (best * W + gy) * W + gx;
      s_val[t] = valid ? 1 : 0;
    } else {
      s_key[t] = -1; s_val[t] = 0;
    }
  }
  __syncthreads();
  if (t < NT && valid) {
    // last valid target with same (anchor,gy,gx) wins (scan overwrite)
    bool win = true;
    int key = s_key[t];
    for (int u = t + 1; u < NT; ++u)
      if (s_val[u] && s_key[u] == key) { win = false; break; }
    if (win) {
      float aw = c_anch[scale][best][0], ah = c_anch[scale][best][1];
      const float* base = pred + (size_t)(n * 75 + best * 25) * HW + gy * W + gx;
      float tx = base[0];
      float ty = base[HW];
      float tw = base[2 * HW];
      float th = base[3 * HW];
      float ob = base[4 * HW];
      int clsi = (int)clsf;                     // trunc toward zero = astype
      bool clsok = (clsi >= 0) && (clsi < NC);
      int clscl = clsi < 0 ? 0 : (clsi > NC - 1 ? NC - 1 : clsi);
      float cv = base[(5 + clscl) * HW];
      float fs = (float)strd;
      // pred box
      float px = (2.f * sigm(tx) - 0.5f + (float)gx) * fs;
      float py = (2.f * sigm(ty) - 0.5f + (float)gy) * fs;
      float sw = 2.f * sigm(tw); float pw = sw * sw * aw * fs;
      float sh = 2.f * sigm(th); float ph = sh * sh * ah * fs;
      // target box (t_wh deliberately has NO stride factor, per reference)
      float qx = ((dx + 0.5f) + (float)gx) * fs;
      float qy = ((dy + 0.5f) + (float)gy) * fs;
      float rw = bw / aw; float qw = rw * rw * aw;
      float rh = bh / ah; float qh = rh * rh * ah;
      // iou_cxcywh
      float b1x1 = px - pw * 0.5f, b1x2 = px + pw * 0.5f;
      float b1y1 = py - ph * 0.5f, b1y2 = py + ph * 0.5f;
      float b2x1 = qx - qw * 0.5f, b2x2 = qx + qw * 0.5f;
      float b2y1 = qy - qh * 0.5f, b2y2 = qy + qh * 0.5f;
      float iw = fmaxf(fminf(b1x2, b2x2) - fmaxf(b1x1, b2x1), 0.f);
      float ih = fmaxf(fminf(b1y2, b2y2) - fmaxf(b1y1, b2y1), 0.f);
      float inter = iw * ih;
      float uni = (b1x2 - b1x1) * (b1y2 - b1y1)
                + (b2x2 - b2x1) * (b2y2 - b2y1) - inter + 1e-7f;
      float iou = inter / uni;
      boxterm = 1.f - iou;
      objc = -ob;                    // bce(x,1)-bce(x,0) = -x
      clsc = clsok ? -cv : 0.f;
      npos = 1.f;
    }
  }
  if (t < 64) {
#pragma unroll
    for (int o = 32; o > 0; o >>= 1) {
      boxterm += __shfl_down(boxterm, o, 64);
      objc    += __shfl_down(objc, o, 64);
      clsc    += __shfl_down(clsc, o, 64);
      npos    += __shfl_down(npos, o, 64);
    }
    if (t == 0) {
      outp[0] = boxterm; outp[1] = objc; outp[2] = clsc; outp[3] = npos;
    }
  }
}

__global__ __launch_bounds__(THREADS)
void yolo_main(const float* __restrict__ p0, const float* __restrict__ p1,
               const float* __restrict__ p2, const float* __restrict__ tg,
               float* __restrict__ ws) {
  int b = blockIdx.x;
  if (b < TGTB) {                       // targets FIRST: overlap latency
    int scale = b / NB, n = b - scale * NB;
    const float* p = scale == 0 ? p0 : (scale == 1 ? p1 : p2);
    target_block(p, tg, scale, n, ws + 4 * (size_t)b);
    return;
  }
  int d = b - TGTB;
  float* outp = ws + WS_DENSE + 2 * (size_t)d;
  if (d < D0)             sum_groups<6400, 4>(p0, d, outp);
  else if (d < D0 + D1)   sum_groups<1600, 2>(p1, d - D0, outp);
  else                    sum_groups<400, 0>(p2, d - (D0 + D1), outp);
}

// ---- parallel finalize ----
// acc layout: [0..5] dense {objSum,clsSum}/scale, [6..17] tgt {box,obj,cls,np}/scale
__global__ __launch_bounds__(THREADS)
void yolo_final(const float* __restrict__ ws, float* __restrict__ out) {
  float acc[18];
#pragma unroll
  for (int k = 0; k < 18; k++) acc[k] = 0.f;
  int t = threadIdx.x;
  for (int b = t; b < DENSB; b += THREADS) {
    int s = (b < D0) ? 0 : (b < D0 + D1 ? 1 : 2);
    const float2 v = *reinterpret_cast<const float2*>(ws + WS_DENSE + 2 * (size_t)b);
    acc[2 * s] += v.x;
    acc[2 * s + 1] += v.y;
  }
  if (t < TGTB) {
    int s = t / NB;
    const float4 v = *reinterpret_cast<const float4*>(ws + 4 * (size_t)t);
    acc[6 + 4 * s + 0] += v.x;
    acc[6 + 4 * s + 1] += v.y;
    acc[6 + 4 * s + 2] += v.z;
    acc[6 + 4 * s + 3] += v.w;
  }
#pragma unroll
  for (int o = 32; o > 0; o >>= 1)
#pragma unroll
    for (int k = 0; k < 18; k++) acc[k] += __shfl_down(acc[k], o, 64);
  __shared__ float red[4][18];
  int wid = t >> 6, lane = t & 63;
  if (lane == 0)
#pragma unroll
    for (int k = 0; k < 18; k++) red[wid][k] = acc[k];
  __syncthreads();
  if (t == 0) {
    float r[18];
#pragma unroll
    for (int k = 0; k < 18; k++)
      r[k] = red[0][k] + red[1][k] + red[2][k] + red[3][k];
    const float objDen[3] = {614400.f, 153600.f, 38400.f};  // N*A*H*W
    float total = 0.f, lb = 0.f, lo = 0.f, lc = 0.f;
    for (int s = 0; s < 3; s++) {
      float np = r[6 + 4 * s + 3];
      float lbs = r[6 + 4 * s + 0] / fmaxf(np, 1.f);
      float los = (r[2 * s] + r[6 + 4 * s + 1]) / objDen[s];
      float lcs = (np > 0.f)
                    ? (r[2 * s + 1] + r[6 + 4 * s + 2]) / (objDen[s] * (float)NC)
                    : 0.f;
      total += 0.05f * lbs + 1.0f * los + 0.5f * lcs;
      lb += lbs; lo += los; lc += lcs;
    }
    out[0] = total; out[1] = lb; out[2] = lo; out[3] = lc;
  }
}

extern "C" void kernel_launch(void* const* d_in, const int* in_sizes, int n_in,
                              void* d_out, int out_size, void* d_ws, size_t ws_size,
                              hipStream_t stream) {
  const float* p0 = (const float*)d_in[0];
  const float* p1 = (const float*)d_in[1];
  const float* p2 = (const float*)d_in[2];
  const float* tg = (const float*)d_in[3];
  float* ws = (float*)d_ws;
  // every ws slot used is written each launch -> no memset needed; fully
  // deterministic (no float atomics, fixed reduction orders).
  yolo_main<<<TGTB + DENSB, THREADS, 0, stream>>>(p0, p1, p2, tg, ws);
  yolo_final<<<1, THREADS, 0, stream>>>(ws, (float*)d_out);
}